// Round 5
// baseline (338.666 us; speedup 1.0000x reference)
//
#include <hip/hip_runtime.h>
#include <hip/hip_bf16.h>

using bf16 = __hip_bfloat16;

typedef __attribute__((ext_vector_type(8))) __bf16 bf16x8;
typedef __attribute__((ext_vector_type(4))) float floatx4;

#define EPS 1e-6f

#define RAW_BARRIER()  asm volatile("s_barrier" ::: "memory")
#define WAIT_VM8()     asm volatile("s_waitcnt vmcnt(8)" ::: "memory")
#define WAIT_VM4()     asm volatile("s_waitcnt vmcnt(4)" ::: "memory")
#define WAIT_VM0()     asm volatile("s_waitcnt vmcnt(0)" ::: "memory")
#define SCHED_FENCE()  __builtin_amdgcn_sched_barrier(0)
#define PRIO1()        __builtin_amdgcn_s_setprio(1)
#define PRIO0()        __builtin_amdgcn_s_setprio(0)

__device__ __forceinline__ void load_lds16(const void* g, void* l) {
    __builtin_amdgcn_global_load_lds(
        (const __attribute__((address_space(1))) void*)g,
        (__attribute__((address_space(3))) void*)l, 16, 0, 0);
}

__device__ __forceinline__ void storeOut(float* p, float v) { *p = v; }
__device__ __forceinline__ void storeOut(bf16* p, float v) { *p = __float2bfloat16(v); }

#define MFMA16(a, b, c) __builtin_amdgcn_mfma_f32_16x16x32_bf16(a, b, c, 0, 0, 0)

// ---------------------------------------------------------------------------
// 2-blocks/CU pipelined NT GEMM: D[m][n] = sum_k A[m][k] * B[n][k]
// BM=BN=128, BK=64 (k-half split), 256 threads = 4 waves (2M x 2N).
// (Unchanged — used for QKV projection and output projection.)
// ---------------------------------------------------------------------------
template <int BIAS_MODE, int RESID_EN, int QKV, typename OutT>
__global__ __launch_bounds__(256, 2) void gemm2b(
    const bf16* __restrict__ A, long long aStride, int lda,
    const bf16* __restrict__ B, long long bStride, int ldb,
    OutT* __restrict__ D, long long dStride, int ldd,
    bf16* __restrict__ vout, long long vStride,
    const float* __restrict__ bias,
    const float* __restrict__ resid, long long rStride, int ldr,
    int K, int tpb, int gx)
{
    constexpr int HB = 8192;   // bytes per (buf, khalf) per operand: 128x32x2B
    extern __shared__ char smem[];

    const unsigned chunk = gridDim.x >> 3;
    const unsigned glob  = (blockIdx.x & 7) * chunk + (blockIdx.x >> 3);
    const unsigned z  = glob / (unsigned)tpb;
    const unsigned t  = glob % (unsigned)tpb;
    const int m0 = (int)(t / (unsigned)gx) << 7;
    const int n0 = (int)(t % (unsigned)gx) << 7;

    const int tid  = threadIdx.x;
    const int lane = tid & 63;
    const int wave = tid >> 6;
    const int wm   = wave >> 1;          // 0..1
    const int wn   = wave & 1;           // 0..1

    const bf16* Ab = A + (size_t)z * aStride + (size_t)m0 * lda;
    const bf16* Bb = B + (size_t)z * bStride + (size_t)n0 * ldb;

    floatx4 acc[4][4];
#pragma unroll
    for (int i = 0; i < 4; ++i)
#pragma unroll
        for (int j = 0; j < 4; ++j) acc[i][j] = (floatx4){0.f, 0.f, 0.f, 0.f};

    const int laneRow = lane & 15;
    const int laneKq  = lane >> 4;
    const int kqs16   = (laneKq ^ ((laneRow >> 1) & 3)) << 4;
    const int arow0   = wm * 64 + laneRow;
    const int brow0   = wn * 64 + laneRow;

    auto stage = [&](int kt, int h) {
        char* Adst = smem + ((kt & 1) * 2 + h) * HB;
        char* Bdst = smem + 4 * HB + ((kt & 1) * 2 + h) * HB;
        const int kb = (kt << 6) + (h << 5);
#pragma unroll
        for (int u = 0; u < 2; ++u) {
            const int idx = tid + u * 256;
            const int r  = idx >> 2;
            const int qs = (idx & 3) ^ ((idx >> 3) & 3);
            load_lds16(Ab + (size_t)r * lda + kb + qs * 8, Adst + idx * 16);
        }
#pragma unroll
        for (int u = 0; u < 2; ++u) {
            const int idx = tid + u * 256;
            const int r  = idx >> 2;
            const int qs = (idx & 3) ^ ((idx >> 3) & 3);
            load_lds16(Bb + (size_t)r * ldb + kb + qs * 8, Bdst + idx * 16);
        }
    };

    const int nt = K >> 6;
    stage(0, 0); stage(0, 1); stage(1, 0);

    for (int kt = 0; kt < nt; ++kt) {
        const char* Ablk = smem + (kt & 1) * 2 * HB;
        const char* Bblk = smem + 4 * HB + (kt & 1) * 2 * HB;
        const bool lastT = (kt == nt - 1);

        // ---- phase 1: k-half 0 ----
        if (lastT) WAIT_VM4(); else WAIT_VM8();
        RAW_BARRIER();
        bf16x8 af[4], bfr[4];
#pragma unroll
        for (int im = 0; im < 4; ++im)
            af[im] = *(const bf16x8*)(Ablk + (arow0 + im * 16) * 64 + kqs16);
#pragma unroll
        for (int in = 0; in < 4; ++in)
            bfr[in] = *(const bf16x8*)(Bblk + (brow0 + in * 16) * 64 + kqs16);
        if (kt + 1 < nt) stage(kt + 1, 1);
        RAW_BARRIER();
        PRIO1();
#pragma unroll
        for (int im = 0; im < 4; ++im)
#pragma unroll
            for (int in = 0; in < 4; ++in)
                acc[im][in] = MFMA16(af[im], bfr[in], acc[im][in]);
        PRIO0();

        // ---- phase 2: k-half 1 ----
        if (lastT) WAIT_VM0(); else WAIT_VM8();
        RAW_BARRIER();
#pragma unroll
        for (int im = 0; im < 4; ++im)
            af[im] = *(const bf16x8*)(Ablk + HB + (arow0 + im * 16) * 64 + kqs16);
#pragma unroll
        for (int in = 0; in < 4; ++in)
            bfr[in] = *(const bf16x8*)(Bblk + HB + (brow0 + in * 16) * 64 + kqs16);
        if (kt + 2 < nt) stage(kt + 2, 0);
        RAW_BARRIER();
        PRIO1();
#pragma unroll
        for (int im = 0; im < 4; ++im)
#pragma unroll
            for (int in = 0; in < 4; ++in)
                acc[im][in] = MFMA16(af[im], bfr[in], acc[im][in]);
        PRIO0();
    }

    // Epilogue. C/D frag layout: col = lane&15, row = (lane>>4)*4 + reg
    const size_t dbase = (size_t)z * dStride;
#pragma unroll
    for (int im = 0; im < 4; ++im) {
        const int gmb = m0 + wm * 64 + im * 16 + (laneKq << 2);
#pragma unroll
        for (int in = 0; in < 4; ++in) {
            const int gn = n0 + wn * 64 + in * 16 + laneRow;
            float bn = 0.f;
            if (BIAS_MODE == 2) bn = bias[gn];
            if (QKV && n0 >= 1024) {
                union { bf16 h[4]; ushort4 u; } pk;
#pragma unroll
                for (int r = 0; r < 4; ++r)
                    pk.h[r] = __float2bfloat16(acc[im][in][r] + bn);
                *(ushort4*)(vout + (size_t)z * vStride +
                            (size_t)(gn - 1024) * 1024 + gmb) = pk.u;
            } else {
#pragma unroll
                for (int r = 0; r < 4; ++r) {
                    const int gm = gmb + r;
                    float v = acc[im][in][r];
                    if (BIAS_MODE == 1) v += bias[gm];
                    if (BIAS_MODE == 2) v += bn;
                    if (RESID_EN)
                        v += resid[(size_t)z * rStride + (size_t)gm * ldr + gn];
                    storeOut(D + dbase + (size_t)gm * ldd + gn, v);
                }
            }
        }
    }
}

// ---------------------------------------------------------------------------
// Fused attention v2: per block, 64 q-rows x full j-sweep.
//   S'[j][i] = K_j . Q_i  (swapped), P = exp(scale*S'), rowsum[i] += P,
//   O[c][i] += V[c][j] * P[j][i], O2[i][c] = O / rowsum.
// Changes vs v1 (which was LDS-pipe-bound at ~50% of its 87.8us, with 4x
// wave duplication of K AND V reads):
//  - V never touches LDS. PV A-frag V[c=laneRow+16mf][j=laneKq*8..+8] is a
//    naturally coalesced global load (wave = 16 rows x 64B = 16 full lines).
//    32 bf16x8 loads issued at the TOP of each tile land under the whole QK
//    phase (L2-resident: XCD-chunked swizzle keeps K+V (4MB) per XCD-pair
//    of batches in the 4MB L2). Halves LDS-pipe load; removes V staging.
//  - K in LDS, TRIPLE-buffered (3x32KB): stage(jt+2) never WAR-races the
//    buffer being read, so one barrier per tile total.
//  - vmcnt ledger (ops retire in issue order): per iter issue V(jt)x32 THEN
//    stageK(jt+2)x8 -> mid-loop vmcnt(8) leaves exactly the K-stage in
//    flight and guarantees all V landed. Top-of-loop vmcnt(8) + barrier
//    covers K(jt) (staged 2 iters ago; only K(jt+1) outstanding). jt>=30:
//    vmcnt(0) (no trailing stage to count against). Max outstanding 48<64.
//  - grid 256 = 1 block/CU = 1 wave/SIMD, so the 512-VGPR budget is free:
//    vf 128 + acc 128 + qf 64 ~ 330 VGPR, no spill expected.
// sched_barrier(0) pins the V-load and stage blocks (hipcc must not sink
// the loads to first use or hoist the stage above them).
// ---------------------------------------------------------------------------
__global__ __launch_bounds__(256, 1) void fattn(
    const bf16* __restrict__ qkT,   // (B,1024,1024): row i = [q_i | k_i]
    const bf16* __restrict__ vv,    // (B,512,1024): [c][j]
    bf16* __restrict__ O2,          // (B,1024,512): [i][c]
    float scale)
{
    constexpr int KT = 32768;           // one K-tile: 32j x 512k bf16 = 32KB
    extern __shared__ char smem[];      // 3 x KT (triple buffer)
    __shared__ __align__(16) char plds[4 * 1024];

    const int bid  = blockIdx.x;
    const int glob = (bid & 7) * 32 + (bid >> 3);   // XCD-chunked
    const int b    = glob >> 4;
    const int i0   = (glob & 15) << 6;

    const int tid     = threadIdx.x;
    const int lane    = tid & 63;
    const int wave    = tid >> 6;
    const int laneRow = lane & 15;
    const int laneKq  = lane >> 4;
    const int kqs16   = (laneKq ^ ((laneRow >> 1) & 3)) << 4;

    const bf16* Qb = qkT + (size_t)b * 1048576 + (size_t)(i0 + wave * 16) * 1024;
    const bf16* Kb = qkT + (size_t)b * 1048576 + 512;
    const bf16* Vb = vv + (size_t)b * 524288 + (size_t)laneRow * 1024 + laneKq * 8;

    // Q fragments: i = laneRow, k = ks*32 + laneKq*8 .. +8
    bf16x8 qf[16];
#pragma unroll
    for (int ks = 0; ks < 16; ++ks)
        qf[ks] = *(const bf16x8*)(Qb + (size_t)laneRow * 1024 + ks * 32 + laneKq * 8);

    floatx4 acc[32];
#pragma unroll
    for (int mf = 0; mf < 32; ++mf) acc[mf] = (floatx4){0.f, 0.f, 0.f, 0.f};
    float rs = 0.f;

    auto stageK = [&](int jt) {
        char* dst = smem + (jt % 3) * KT;
        const bf16* src = Kb + ((size_t)jt << 5) * 1024;
#pragma unroll
        for (int u = 0; u < 8; ++u) {
            const int idx = tid + u * 256;          // 0..2047
            const int kk = idx >> 7;                // k sub-block 0..15
            const int j  = (idx >> 2) & 31;
            const int p  = idx & 3;
            load_lds16(src + (size_t)j * 1024 + kk * 32 + 8 * (p ^ ((j >> 1) & 3)),
                       dst + idx * 16);
        }
    };

    stageK(0); stageK(1);                // 16 outstanding

    char* pl = plds + wave * 1024 + laneRow * 64;
    const int sw2 = ((laneRow >> 1) & 3) << 1;      // 8B-granule XOR mask

    for (int jt = 0; jt < 32; ++jt) {
        WAIT_VM8();                      // K(jt) done (only K(jt+1) newer)
        RAW_BARRIER();
        const char* Kt = smem + (jt % 3) * KT;

        // ---- issue V(jt) global->VGPR (lands under QK), then K-stage ----
        bf16x8 vf[32];
        const bf16* vsrc = Vb + (jt << 5);
#pragma unroll
        for (int mf = 0; mf < 32; ++mf)
            vf[mf] = *(const bf16x8*)(vsrc + (size_t)mf * 16384);
        SCHED_FENCE();
        if (jt + 2 < 32) stageK(jt + 2);
        SCHED_FENCE();

        // ---- S' = K_tile . Q : P[j][i], j split in 2 m-frags ----
        floatx4 s0 = (floatx4){0.f, 0.f, 0.f, 0.f};
        floatx4 s1 = (floatx4){0.f, 0.f, 0.f, 0.f};
#pragma unroll
        for (int ks = 0; ks < 16; ++ks) {
            bf16x8 kf0 = *(const bf16x8*)(Kt + ks * 2048 + laneRow * 64 + kqs16);
            bf16x8 kf1 = *(const bf16x8*)(Kt + ks * 2048 + (laneRow + 16) * 64 + kqs16);
            s0 = MFMA16(kf0, qf[ks], s0);
            s1 = MFMA16(kf1, qf[ks], s1);
        }

        // ---- exp + rowsum + P -> wave-private LDS (granule-XOR layout) ----
        union { bf16 h[4]; unsigned long long u; } w0, w1;
#pragma unroll
        for (int r = 0; r < 4; ++r) {
            float v0 = __expf(s0[r] * scale);
            float v1 = __expf(s1[r] * scale);
            rs += v0 + v1;
            w0.h[r] = __float2bfloat16(v0);
            w1.h[r] = __float2bfloat16(v1);
        }
        *(unsigned long long*)(pl + ((laneKq)     ^ sw2) * 8) = w0.u;
        *(unsigned long long*)(pl + ((laneKq + 4) ^ sw2) * 8) = w1.u;
        asm volatile("s_waitcnt lgkmcnt(0)" ::: "memory");
        SCHED_FENCE();
        bf16x8 pf = *(const bf16x8*)(pl + kqs16);

        // ---- wait V; K(jt+2) stage (the newest 8) stays in flight ----
        if (jt >= 30) WAIT_VM0(); else WAIT_VM8();

        // ---- O[c][i] += V . P ----
        PRIO1();
#pragma unroll
        for (int mf = 0; mf < 32; ++mf)
            acc[mf] = MFMA16(vf[mf], pf, acc[mf]);
        PRIO0();
    }

    // rowsum: lane holds partial for i = lane&15; reduce across lane groups
    rs += __shfl_xor(rs, 16);
    rs += __shfl_xor(rs, 32);
    const float ri = 1.f / rs;

    // O2[i][c] = acc[c][i] * ri ; c = 16*mf + 4*laneKq + r, i = laneRow
    bf16* Ob = O2 + (size_t)b * 524288 +
               (size_t)(i0 + wave * 16 + laneRow) * 512 + (laneKq << 2);
#pragma unroll
    for (int mf = 0; mf < 32; ++mf) {
        union { bf16 h[4]; ushort4 u; } pk;
#pragma unroll
        for (int r = 0; r < 4; ++r)
            pk.h[r] = __float2bfloat16(acc[mf][r] * ri);
        *(ushort4*)(Ob + mf * 16) = pk.u;
    }
}

// ---------------------------------------------------------------------------
// GroupNorm stats: one block per (b, g); 16 ch x 1024 = 16384 contiguous floats
// ---------------------------------------------------------------------------
__global__ __launch_bounds__(256) void gn_stats(const float* __restrict__ x,
                                                float* __restrict__ stats)
{
    const int bg = blockIdx.x;
    const float4* p = (const float4*)(x + (size_t)bg * 16384);
    float s = 0.f, ss = 0.f;
    for (int i = threadIdx.x; i < 4096; i += 256) {
        float4 v = p[i];
        s  += v.x + v.y + v.z + v.w;
        ss += v.x * v.x + v.y * v.y + v.z * v.z + v.w * v.w;
    }
#pragma unroll
    for (int off = 32; off; off >>= 1) {
        s  += __shfl_down(s, off);
        ss += __shfl_down(ss, off);
    }
    __shared__ float rs[4], rss[4];
    const int wv = threadIdx.x >> 6;
    if ((threadIdx.x & 63) == 0) { rs[wv] = s; rss[wv] = ss; }
    __syncthreads();
    if (threadIdx.x == 0) {
        float S  = rs[0] + rs[1] + rs[2] + rs[3];
        float SS = rss[0] + rss[1] + rss[2] + rss[3];
        float mean = S * (1.f / 16384.f);
        float var  = SS * (1.f / 16384.f) - mean * mean;
        stats[2 * bg]     = mean;
        stats[2 * bg + 1] = rsqrtf(var + EPS);
    }
}

// ---------------------------------------------------------------------------
// GN apply + transpose: x (B,512,1024) fp32 -> xnT (B,1024,512) bf16
// ---------------------------------------------------------------------------
__global__ __launch_bounds__(256) void gn_apply_t(const float* __restrict__ x,
                                                  const float* __restrict__ stats,
                                                  const float* __restrict__ gamma,
                                                  const float* __restrict__ beta,
                                                  bf16* __restrict__ xnT)
{
    __shared__ bf16 tile[32][36];
    const int b = blockIdx.z, c0 = blockIdx.y * 32, i0 = blockIdx.x * 32;
    {
        const int cc = threadIdx.x >> 3;
        const int i4 = (threadIdx.x & 7) << 2;
        const int c  = c0 + cc;
        const float mean = stats[2 * ((b << 5) + (c >> 4))];
        const float rstd = stats[2 * ((b << 5) + (c >> 4)) + 1];
        const float a  = gamma[c] * rstd;
        const float bb = beta[c] - mean * a;
        float4 v = *(const float4*)(x + (((size_t)(b * 512 + c)) << 10) + i0 + i4);
        tile[cc][i4 + 0] = __float2bfloat16(v.x * a + bb);
        tile[cc][i4 + 1] = __float2bfloat16(v.y * a + bb);
        tile[cc][i4 + 2] = __float2bfloat16(v.z * a + bb);
        tile[cc][i4 + 3] = __float2bfloat16(v.w * a + bb);
    }
    __syncthreads();
    {
        const int ii = threadIdx.x >> 3;
        const int c4 = (threadIdx.x & 7) << 2;
        union { bf16 h[4]; uint2 u; } pk;
        pk.h[0] = tile[c4 + 0][ii];
        pk.h[1] = tile[c4 + 1][ii];
        pk.h[2] = tile[c4 + 2][ii];
        pk.h[3] = tile[c4 + 3][ii];
        *((uint2*)(xnT + (((size_t)(b * 1024 + i0 + ii)) << 9) + c0 + c4)) = pk.u;
    }
}

// ---------------------------------------------------------------------------
// prep: weights fp32->bf16 (blocks 0..1023), qkv bias concat (block 1024).
// ---------------------------------------------------------------------------
__global__ __launch_bounds__(256) void prep(
    const float* __restrict__ wq, const float* __restrict__ wk,
    const float* __restrict__ wv, const float* __restrict__ wp,
    bf16* __restrict__ wqkvb, bf16* __restrict__ wpb,
    const float* __restrict__ bq, const float* __restrict__ bk,
    const float* __restrict__ bv, float* __restrict__ bqkv)
{
    const int id = blockIdx.x;
    if (id < 1024) {
        const int w = id >> 8;
        const float* src = (w == 0) ? wq : (w == 1) ? wk : (w == 2) ? wv : wp;
        bf16* dst = (w < 3) ? (wqkvb + (size_t)w * 262144) : wpb;
        const int g = (id & 255) * 256 + threadIdx.x;
        float4 v = ((const float4*)src)[g];
        union { bf16 h[4]; uint2 u; } pk;
        pk.h[0] = __float2bfloat16(v.x);
        pk.h[1] = __float2bfloat16(v.y);
        pk.h[2] = __float2bfloat16(v.z);
        pk.h[3] = __float2bfloat16(v.w);
        ((uint2*)dst)[g] = pk.u;
    } else {
        for (int t = threadIdx.x; t < 1536; t += 256)
            bqkv[t] = (t < 512) ? bq[t] : (t < 1024) ? bk[t - 512] : bv[t - 1024];
    }
}

// ---------------------------------------------------------------------------
extern "C" void kernel_launch(void* const* d_in, const int* in_sizes, int n_in,
                              void* d_out, int out_size, void* d_ws, size_t ws_size,
                              hipStream_t stream)
{
    const float* x     = (const float*)d_in[0];
    const float* gamma = (const float*)d_in[1];
    const float* beta  = (const float*)d_in[2];
    const float* wq    = (const float*)d_in[3];
    const float* bq    = (const float*)d_in[4];
    const float* wk    = (const float*)d_in[5];
    const float* bk    = (const float*)d_in[6];
    const float* wv    = (const float*)d_in[7];
    const float* bv    = (const float*)d_in[8];
    const float* wp    = (const float*)d_in[9];
    const float* bp    = (const float*)d_in[10];
    float* out = (float*)d_out;

    char* ws = (char*)d_ws;
    size_t off = 0;
    auto alloc = [&](size_t bytes) -> char* {
        char* p = ws + off;
        off += (bytes + 255) & ~(size_t)255;
        return p;
    };

    const long long S  = 1024, C = 512;
    const long long BS = S * C;
    const long long ES = S * S;

    float* stats  = (float*)alloc(512 * 2 * sizeof(float));
    float* bqkv   = (float*)alloc(1536 * sizeof(float));
    bf16* wqkvb = (bf16*)alloc((size_t)3 * C * C * 2);  // [wq; wk; wv]
    bf16* wpb   = (bf16*)alloc((size_t)C * C * 2);
    bf16* xnT   = (bf16*)alloc((size_t)16 * BS * 2);
    bf16* qkT   = (bf16*)alloc((size_t)16 * ES * 2);    // (B,1024,1024): [qT|kT]
    bf16* vv    = (bf16*)alloc((size_t)16 * BS * 2);    // (B,512,1024)
    bf16* O2    = (bf16*)alloc((size_t)16 * BS * 2);

    // Dynamic LDS caps (immediate module state; graph-capture safe).
    hipFuncSetAttribute((const void*)gemm2b<2, 0, 1, bf16>,
                        hipFuncAttributeMaxDynamicSharedMemorySize, 65536);
    hipFuncSetAttribute((const void*)gemm2b<1, 1, 0, float>,
                        hipFuncAttributeMaxDynamicSharedMemorySize, 65536);
    hipFuncSetAttribute((const void*)fattn,
                        hipFuncAttributeMaxDynamicSharedMemorySize, 98304);

    prep<<<1025, 256, 0, stream>>>(wq, wk, wv, wp, wqkvb, wpb, bq, bk, bv, bqkv);

    gn_stats<<<512, 256, 0, stream>>>(x, stats);
    gn_apply_t<<<dim3(32, 16, 16), 256, 0, stream>>>(x, stats, gamma, beta, xnT);

    // QKV proj: M=1024 (i), N=1536 ([q|k|v]), K=512, Z=16. 8x12x16 = 1536 blk.
    gemm2b<2, 0, 1, bf16><<<1536, 256, 65536, stream>>>(
        xnT, BS, 512, wqkvb, 0, 512, qkT, ES, 1024, vv, BS,
        bqkv, nullptr, 0, 0, 512, /*tpb*/96, /*gx*/12);

    const float scale = 0.044194173824159216f; // 512^-0.5
    // Fused attention: 16 batches x 16 i-tiles = 256 blocks, 1/CU.
    fattn<<<256, 256, 98304, stream>>>(qkT, vv, O2, scale);

    // out[o][i] = sum_c wp[o][c] O2[i][c] + bp[o] + x[o][i]. 4x8 tiles x16.
    gemm2b<1, 1, 0, float><<<512, 256, 65536, stream>>>(
        wpb, 0, 512, O2, BS, 512, out, BS, 1024, nullptr, 0,
        bp, x, BS, 1024, 512, /*tpb*/32, /*gx*/8);
}

// Round 6
// 333.515 us; speedup vs baseline: 1.0154x; 1.0154x over previous
//
#include <hip/hip_runtime.h>
#include <hip/hip_bf16.h>

using bf16 = __hip_bfloat16;

typedef __attribute__((ext_vector_type(8))) __bf16 bf16x8;
typedef __attribute__((ext_vector_type(4))) float floatx4;

#define EPS 1e-6f

#define RAW_BARRIER()  asm volatile("s_barrier" ::: "memory")
#define WAIT_VM8()     asm volatile("s_waitcnt vmcnt(8)" ::: "memory")
#define WAIT_VM4()     asm volatile("s_waitcnt vmcnt(4)" ::: "memory")
#define WAIT_VM0()     asm volatile("s_waitcnt vmcnt(0)" ::: "memory")
#define SCHED_FENCE()  __builtin_amdgcn_sched_barrier(0)
#define PRIO1()        __builtin_amdgcn_s_setprio(1)
#define PRIO0()        __builtin_amdgcn_s_setprio(0)

__device__ __forceinline__ void load_lds16(const void* g, void* l) {
    __builtin_amdgcn_global_load_lds(
        (const __attribute__((address_space(1))) void*)g,
        (__attribute__((address_space(3))) void*)l, 16, 0, 0);
}

__device__ __forceinline__ void storeOut(float* p, float v) { *p = v; }
__device__ __forceinline__ void storeOut(bf16* p, float v) { *p = __float2bfloat16(v); }

#define MFMA16(a, b, c) __builtin_amdgcn_mfma_f32_16x16x32_bf16(a, b, c, 0, 0, 0)

// ---------------------------------------------------------------------------
// 2-blocks/CU pipelined NT GEMM: D[m][n] = sum_k A[m][k] * B[n][k]
// BM=BN=128, BK=64 (k-half split), 256 threads = 4 waves (2M x 2N).
// (Unchanged — used for QKV projection and output projection.)
// ---------------------------------------------------------------------------
template <int BIAS_MODE, int RESID_EN, int QKV, typename OutT>
__global__ __launch_bounds__(256, 2) void gemm2b(
    const bf16* __restrict__ A, long long aStride, int lda,
    const bf16* __restrict__ B, long long bStride, int ldb,
    OutT* __restrict__ D, long long dStride, int ldd,
    bf16* __restrict__ vout, long long vStride,
    const float* __restrict__ bias,
    const float* __restrict__ resid, long long rStride, int ldr,
    int K, int tpb, int gx)
{
    constexpr int HB = 8192;   // bytes per (buf, khalf) per operand: 128x32x2B
    extern __shared__ char smem[];

    const unsigned chunk = gridDim.x >> 3;
    const unsigned glob  = (blockIdx.x & 7) * chunk + (blockIdx.x >> 3);
    const unsigned z  = glob / (unsigned)tpb;
    const unsigned t  = glob % (unsigned)tpb;
    const int m0 = (int)(t / (unsigned)gx) << 7;
    const int n0 = (int)(t % (unsigned)gx) << 7;

    const int tid  = threadIdx.x;
    const int lane = tid & 63;
    const int wave = tid >> 6;
    const int wm   = wave >> 1;          // 0..1
    const int wn   = wave & 1;           // 0..1

    const bf16* Ab = A + (size_t)z * aStride + (size_t)m0 * lda;
    const bf16* Bb = B + (size_t)z * bStride + (size_t)n0 * ldb;

    floatx4 acc[4][4];
#pragma unroll
    for (int i = 0; i < 4; ++i)
#pragma unroll
        for (int j = 0; j < 4; ++j) acc[i][j] = (floatx4){0.f, 0.f, 0.f, 0.f};

    const int laneRow = lane & 15;
    const int laneKq  = lane >> 4;
    const int kqs16   = (laneKq ^ ((laneRow >> 1) & 3)) << 4;
    const int arow0   = wm * 64 + laneRow;
    const int brow0   = wn * 64 + laneRow;

    auto stage = [&](int kt, int h) {
        char* Adst = smem + ((kt & 1) * 2 + h) * HB;
        char* Bdst = smem + 4 * HB + ((kt & 1) * 2 + h) * HB;
        const int kb = (kt << 6) + (h << 5);
#pragma unroll
        for (int u = 0; u < 2; ++u) {
            const int idx = tid + u * 256;
            const int r  = idx >> 2;
            const int qs = (idx & 3) ^ ((idx >> 3) & 3);
            load_lds16(Ab + (size_t)r * lda + kb + qs * 8, Adst + idx * 16);
        }
#pragma unroll
        for (int u = 0; u < 2; ++u) {
            const int idx = tid + u * 256;
            const int r  = idx >> 2;
            const int qs = (idx & 3) ^ ((idx >> 3) & 3);
            load_lds16(Bb + (size_t)r * ldb + kb + qs * 8, Bdst + idx * 16);
        }
    };

    const int nt = K >> 6;
    stage(0, 0); stage(0, 1); stage(1, 0);

    for (int kt = 0; kt < nt; ++kt) {
        const char* Ablk = smem + (kt & 1) * 2 * HB;
        const char* Bblk = smem + 4 * HB + (kt & 1) * 2 * HB;
        const bool lastT = (kt == nt - 1);

        // ---- phase 1: k-half 0 ----
        if (lastT) WAIT_VM4(); else WAIT_VM8();
        RAW_BARRIER();
        bf16x8 af[4], bfr[4];
#pragma unroll
        for (int im = 0; im < 4; ++im)
            af[im] = *(const bf16x8*)(Ablk + (arow0 + im * 16) * 64 + kqs16);
#pragma unroll
        for (int in = 0; in < 4; ++in)
            bfr[in] = *(const bf16x8*)(Bblk + (brow0 + in * 16) * 64 + kqs16);
        if (kt + 1 < nt) stage(kt + 1, 1);
        RAW_BARRIER();
        PRIO1();
#pragma unroll
        for (int im = 0; im < 4; ++im)
#pragma unroll
            for (int in = 0; in < 4; ++in)
                acc[im][in] = MFMA16(af[im], bfr[in], acc[im][in]);
        PRIO0();

        // ---- phase 2: k-half 1 ----
        if (lastT) WAIT_VM0(); else WAIT_VM8();
        RAW_BARRIER();
#pragma unroll
        for (int im = 0; im < 4; ++im)
            af[im] = *(const bf16x8*)(Ablk + HB + (arow0 + im * 16) * 64 + kqs16);
#pragma unroll
        for (int in = 0; in < 4; ++in)
            bfr[in] = *(const bf16x8*)(Bblk + HB + (brow0 + in * 16) * 64 + kqs16);
        if (kt + 2 < nt) stage(kt + 2, 0);
        RAW_BARRIER();
        PRIO1();
#pragma unroll
        for (int im = 0; im < 4; ++im)
#pragma unroll
            for (int in = 0; in < 4; ++in)
                acc[im][in] = MFMA16(af[im], bfr[in], acc[im][in]);
        PRIO0();
    }

    // Epilogue. C/D frag layout: col = lane&15, row = (lane>>4)*4 + reg
    const size_t dbase = (size_t)z * dStride;
#pragma unroll
    for (int im = 0; im < 4; ++im) {
        const int gmb = m0 + wm * 64 + im * 16 + (laneKq << 2);
#pragma unroll
        for (int in = 0; in < 4; ++in) {
            const int gn = n0 + wn * 64 + in * 16 + laneRow;
            float bn = 0.f;
            if (BIAS_MODE == 2) bn = bias[gn];
            if (QKV && n0 >= 1024) {
                union { bf16 h[4]; ushort4 u; } pk;
#pragma unroll
                for (int r = 0; r < 4; ++r)
                    pk.h[r] = __float2bfloat16(acc[im][in][r] + bn);
                *(ushort4*)(vout + (size_t)z * vStride +
                            (size_t)(gn - 1024) * 1024 + gmb) = pk.u;
            } else {
#pragma unroll
                for (int r = 0; r < 4; ++r) {
                    const int gm = gmb + r;
                    float v = acc[im][in][r];
                    if (BIAS_MODE == 1) v += bias[gm];
                    if (BIAS_MODE == 2) v += bn;
                    if (RESID_EN)
                        v += resid[(size_t)z * rStride + (size_t)gm * ldr + gn];
                    storeOut(D + dbase + (size_t)gm * ldd + gn, v);
                }
            }
        }
    }
}

// ---------------------------------------------------------------------------
// Fused attention v3: per block, 64 q-rows x full j-sweep.
//   S'[j][i] = K_j . Q_i (swapped), P = exp(scale*S'), rowsum[i] += P,
//   O[c][i] += V[c][j] * P[j][i], O2[i][c] = O / rowsum.
// v1 (R4, 87.8us) was LDS-pipe-bound: per tile per CU ~268 ds ops (~50% of
// kernel time), half of them V fragments duplicated across 4 waves.
// v2 (R5) moved all 32 V frags to VGPRs at once -> 128 regs live across QK
// -> compiler spilled (192 VGPR), 174us. v3 keeps the idea with BOUNDED
// registers: ping-pong V chunks of 8 frags (vA/vB, 64 VGPR peak, short
// live ranges, static indexing).
// Per tile: top vmcnt(8)+barrier (K(jt) landed; only K(jt+1)-stage older
// outstanding); issue V chunk0 (lands under whole QK phase); QK from LDS;
// exp+P roundtrip (wave-private LDS); PV = 4x { issue next chunk;
// vmcnt(8) [in-order retirement: leaves only newest chunk -> previous
// chunk AND any older K-stage landed]; 8 MFMA }; last chunk vmcnt(0)
// (nothing newer in flight; stage(jt+2) not yet issued); bottom barrier;
// stageK(jt+2) into buf jt&1 (all waves done reading K(jt) - WAR safe).
// V frag V[c=laneRow+16mf][j=laneKq*8..+8]: wave = 16 rows x 64B = 16 full
// cache lines, L2-resident (XCD-chunked swizzle: 2 batches K+V = 4MB/XCD).
// LDS ops/tile/CU: ~140 vs 268 in v1; V rides the parallel L2 pipe.
// ---------------------------------------------------------------------------
__global__ __launch_bounds__(256, 1) void fattn(
    const bf16* __restrict__ qkT,   // (B,1024,1024): row i = [q_i | k_i]
    const bf16* __restrict__ vv,    // (B,512,1024): [c][j]
    bf16* __restrict__ O2,          // (B,1024,512): [i][c]
    float scale)
{
    constexpr int KT = 32768;           // one K-tile: 32j x 512k bf16 = 32KB
    extern __shared__ char smem[];      // 2 x KT (double buffer)
    __shared__ __align__(16) char plds[4 * 1024];

    const int bid  = blockIdx.x;
    const int glob = (bid & 7) * 32 + (bid >> 3);   // XCD-chunked
    const int b    = glob >> 4;
    const int i0   = (glob & 15) << 6;

    const int tid     = threadIdx.x;
    const int lane    = tid & 63;
    const int wave    = tid >> 6;
    const int laneRow = lane & 15;
    const int laneKq  = lane >> 4;
    const int kqs16   = (laneKq ^ ((laneRow >> 1) & 3)) << 4;

    const bf16* Qb = qkT + (size_t)b * 1048576 + (size_t)(i0 + wave * 16) * 1024;
    const bf16* Kb = qkT + (size_t)b * 1048576 + 512;
    const bf16* Vb = vv + (size_t)b * 524288 + (size_t)laneRow * 1024 + laneKq * 8;

    // Q fragments: i = laneRow, k = ks*32 + laneKq*8 .. +8
    bf16x8 qf[16];
#pragma unroll
    for (int ks = 0; ks < 16; ++ks)
        qf[ks] = *(const bf16x8*)(Qb + (size_t)laneRow * 1024 + ks * 32 + laneKq * 8);

    floatx4 acc[32];
#pragma unroll
    for (int mf = 0; mf < 32; ++mf) acc[mf] = (floatx4){0.f, 0.f, 0.f, 0.f};
    float rs = 0.f;

    auto stageK = [&](int jt) {
        char* dst = smem + (jt & 1) * KT;
        const bf16* src = Kb + ((size_t)jt << 5) * 1024;
#pragma unroll
        for (int u = 0; u < 8; ++u) {
            const int idx = tid + u * 256;          // 0..2047
            const int kk = idx >> 7;                // k sub-block 0..15
            const int j  = (idx >> 2) & 31;
            const int p  = idx & 3;
            load_lds16(src + (size_t)j * 1024 + kk * 32 + 8 * (p ^ ((j >> 1) & 3)),
                       dst + idx * 16);
        }
    };

    stageK(0); stageK(1);                // 16 outstanding

    char* pl = plds + wave * 1024 + laneRow * 64;
    const int sw2 = ((laneRow >> 1) & 3) << 1;      // 8B-granule XOR mask

    for (int jt = 0; jt < 32; ++jt) {
        WAIT_VM8();                      // K(jt) landed (only K(jt+1) newer)
        RAW_BARRIER();
        const char* Kt = smem + (jt & 1) * KT;
        const bf16* vsrc = Vb + (jt << 5);

        // ---- issue V chunk 0 (mf 0..7): lands under the QK phase ----
        bf16x8 vA[8], vB[8];
#pragma unroll
        for (int u = 0; u < 8; ++u)
            vA[u] = *(const bf16x8*)(vsrc + (size_t)u * 16384);
        SCHED_FENCE();

        // ---- S' = K_tile . Q : P[j][i], j split in 2 m-frags ----
        floatx4 s0 = (floatx4){0.f, 0.f, 0.f, 0.f};
        floatx4 s1 = (floatx4){0.f, 0.f, 0.f, 0.f};
#pragma unroll
        for (int ks = 0; ks < 16; ++ks) {
            bf16x8 kf0 = *(const bf16x8*)(Kt + ks * 2048 + laneRow * 64 + kqs16);
            bf16x8 kf1 = *(const bf16x8*)(Kt + ks * 2048 + (laneRow + 16) * 64 + kqs16);
            s0 = MFMA16(kf0, qf[ks], s0);
            s1 = MFMA16(kf1, qf[ks], s1);
        }

        // ---- exp + rowsum + P -> wave-private LDS (granule-XOR layout) ----
        union { bf16 h[4]; unsigned long long u; } w0, w1;
#pragma unroll
        for (int r = 0; r < 4; ++r) {
            float v0 = __expf(s0[r] * scale);
            float v1 = __expf(s1[r] * scale);
            rs += v0 + v1;
            w0.h[r] = __float2bfloat16(v0);
            w1.h[r] = __float2bfloat16(v1);
        }
        *(unsigned long long*)(pl + ((laneKq)     ^ sw2) * 8) = w0.u;
        *(unsigned long long*)(pl + ((laneKq + 4) ^ sw2) * 8) = w1.u;
        asm volatile("s_waitcnt lgkmcnt(0)" ::: "memory");
        SCHED_FENCE();
        bf16x8 pf = *(const bf16x8*)(pl + kqs16);

        // ---- PV, 4 ping-pong chunks of 8 ----
        // chunk 1 -> vB; wait c0 (vmcnt(8) leaves only c1); MFMA c0
#pragma unroll
        for (int u = 0; u < 8; ++u)
            vB[u] = *(const bf16x8*)(vsrc + (size_t)(u + 8) * 16384);
        SCHED_FENCE();
        WAIT_VM8();
        PRIO1();
#pragma unroll
        for (int u = 0; u < 8; ++u) acc[u] = MFMA16(vA[u], pf, acc[u]);
        PRIO0();
        // chunk 2 -> vA; wait c1; MFMA c1
#pragma unroll
        for (int u = 0; u < 8; ++u)
            vA[u] = *(const bf16x8*)(vsrc + (size_t)(u + 16) * 16384);
        SCHED_FENCE();
        WAIT_VM8();
        PRIO1();
#pragma unroll
        for (int u = 0; u < 8; ++u) acc[u + 8] = MFMA16(vB[u], pf, acc[u + 8]);
        PRIO0();
        // chunk 3 -> vB; wait c2; MFMA c2
#pragma unroll
        for (int u = 0; u < 8; ++u)
            vB[u] = *(const bf16x8*)(vsrc + (size_t)(u + 24) * 16384);
        SCHED_FENCE();
        WAIT_VM8();
        PRIO1();
#pragma unroll
        for (int u = 0; u < 8; ++u) acc[u + 16] = MFMA16(vA[u], pf, acc[u + 16]);
        PRIO0();
        // wait c3 (nothing newer in flight); MFMA c3
        WAIT_VM0();
        PRIO1();
#pragma unroll
        for (int u = 0; u < 8; ++u) acc[u + 24] = MFMA16(vB[u], pf, acc[u + 24]);
        PRIO0();

        RAW_BARRIER();                   // all waves done reading K(jt)
        if (jt + 2 < 32) stageK(jt + 2); // WAR-safe into buf jt&1
    }

    // rowsum: lane holds partial for i = lane&15; reduce across lane groups
    rs += __shfl_xor(rs, 16);
    rs += __shfl_xor(rs, 32);
    const float ri = 1.f / rs;

    // O2[i][c] = acc[c][i] * ri ; c = 16*mf + 4*laneKq + r, i = laneRow
    bf16* Ob = O2 + (size_t)b * 524288 +
               (size_t)(i0 + wave * 16 + laneRow) * 512 + (laneKq << 2);
#pragma unroll
    for (int mf = 0; mf < 32; ++mf) {
        union { bf16 h[4]; ushort4 u; } pk;
#pragma unroll
        for (int r = 0; r < 4; ++r)
            pk.h[r] = __float2bfloat16(acc[mf][r] * ri);
        *(ushort4*)(Ob + mf * 16) = pk.u;
    }
}

// ---------------------------------------------------------------------------
// GroupNorm stats: one block per (b, g); 16 ch x 1024 = 16384 contiguous floats
// ---------------------------------------------------------------------------
__global__ __launch_bounds__(256) void gn_stats(const float* __restrict__ x,
                                                float* __restrict__ stats)
{
    const int bg = blockIdx.x;
    const float4* p = (const float4*)(x + (size_t)bg * 16384);
    float s = 0.f, ss = 0.f;
    for (int i = threadIdx.x; i < 4096; i += 256) {
        float4 v = p[i];
        s  += v.x + v.y + v.z + v.w;
        ss += v.x * v.x + v.y * v.y + v.z * v.z + v.w * v.w;
    }
#pragma unroll
    for (int off = 32; off; off >>= 1) {
        s  += __shfl_down(s, off);
        ss += __shfl_down(ss, off);
    }
    __shared__ float rs[4], rss[4];
    const int wv = threadIdx.x >> 6;
    if ((threadIdx.x & 63) == 0) { rs[wv] = s; rss[wv] = ss; }
    __syncthreads();
    if (threadIdx.x == 0) {
        float S  = rs[0] + rs[1] + rs[2] + rs[3];
        float SS = rss[0] + rss[1] + rss[2] + rss[3];
        float mean = S * (1.f / 16384.f);
        float var  = SS * (1.f / 16384.f) - mean * mean;
        stats[2 * bg]     = mean;
        stats[2 * bg + 1] = rsqrtf(var + EPS);
    }
}

// ---------------------------------------------------------------------------
// GN apply + transpose: x (B,512,1024) fp32 -> xnT (B,1024,512) bf16
// ---------------------------------------------------------------------------
__global__ __launch_bounds__(256) void gn_apply_t(const float* __restrict__ x,
                                                  const float* __restrict__ stats,
                                                  const float* __restrict__ gamma,
                                                  const float* __restrict__ beta,
                                                  bf16* __restrict__ xnT)
{
    __shared__ bf16 tile[32][36];
    const int b = blockIdx.z, c0 = blockIdx.y * 32, i0 = blockIdx.x * 32;
    {
        const int cc = threadIdx.x >> 3;
        const int i4 = (threadIdx.x & 7) << 2;
        const int c  = c0 + cc;
        const float mean = stats[2 * ((b << 5) + (c >> 4))];
        const float rstd = stats[2 * ((b << 5) + (c >> 4)) + 1];
        const float a  = gamma[c] * rstd;
        const float bb = beta[c] - mean * a;
        float4 v = *(const float4*)(x + (((size_t)(b * 512 + c)) << 10) + i0 + i4);
        tile[cc][i4 + 0] = __float2bfloat16(v.x * a + bb);
        tile[cc][i4 + 1] = __float2bfloat16(v.y * a + bb);
        tile[cc][i4 + 2] = __float2bfloat16(v.z * a + bb);
        tile[cc][i4 + 3] = __float2bfloat16(v.w * a + bb);
    }
    __syncthreads();
    {
        const int ii = threadIdx.x >> 3;
        const int c4 = (threadIdx.x & 7) << 2;
        union { bf16 h[4]; uint2 u; } pk;
        pk.h[0] = tile[c4 + 0][ii];
        pk.h[1] = tile[c4 + 1][ii];
        pk.h[2] = tile[c4 + 2][ii];
        pk.h[3] = tile[c4 + 3][ii];
        *((uint2*)(xnT + (((size_t)(b * 1024 + i0 + ii)) << 9) + c0 + c4)) = pk.u;
    }
}

// ---------------------------------------------------------------------------
// prep: weights fp32->bf16 (blocks 0..1023), qkv bias concat (block 1024).
// ---------------------------------------------------------------------------
__global__ __launch_bounds__(256) void prep(
    const float* __restrict__ wq, const float* __restrict__ wk,
    const float* __restrict__ wv, const float* __restrict__ wp,
    bf16* __restrict__ wqkvb, bf16* __restrict__ wpb,
    const float* __restrict__ bq, const float* __restrict__ bk,
    const float* __restrict__ bv, float* __restrict__ bqkv)
{
    const int id = blockIdx.x;
    if (id < 1024) {
        const int w = id >> 8;
        const float* src = (w == 0) ? wq : (w == 1) ? wk : (w == 2) ? wv : wp;
        bf16* dst = (w < 3) ? (wqkvb + (size_t)w * 262144) : wpb;
        const int g = (id & 255) * 256 + threadIdx.x;
        float4 v = ((const float4*)src)[g];
        union { bf16 h[4]; uint2 u; } pk;
        pk.h[0] = __float2bfloat16(v.x);
        pk.h[1] = __float2bfloat16(v.y);
        pk.h[2] = __float2bfloat16(v.z);
        pk.h[3] = __float2bfloat16(v.w);
        ((uint2*)dst)[g] = pk.u;
    } else {
        for (int t = threadIdx.x; t < 1536; t += 256)
            bqkv[t] = (t < 512) ? bq[t] : (t < 1024) ? bk[t - 512] : bv[t - 1024];
    }
}

// ---------------------------------------------------------------------------
extern "C" void kernel_launch(void* const* d_in, const int* in_sizes, int n_in,
                              void* d_out, int out_size, void* d_ws, size_t ws_size,
                              hipStream_t stream)
{
    const float* x     = (const float*)d_in[0];
    const float* gamma = (const float*)d_in[1];
    const float* beta  = (const float*)d_in[2];
    const float* wq    = (const float*)d_in[3];
    const float* bq    = (const float*)d_in[4];
    const float* wk    = (const float*)d_in[5];
    const float* bk    = (const float*)d_in[6];
    const float* wv    = (const float*)d_in[7];
    const float* bv    = (const float*)d_in[8];
    const float* wp    = (const float*)d_in[9];
    const float* bp    = (const float*)d_in[10];
    float* out = (float*)d_out;

    char* ws = (char*)d_ws;
    size_t off = 0;
    auto alloc = [&](size_t bytes) -> char* {
        char* p = ws + off;
        off += (bytes + 255) & ~(size_t)255;
        return p;
    };

    const long long S  = 1024, C = 512;
    const long long BS = S * C;
    const long long ES = S * S;

    float* stats  = (float*)alloc(512 * 2 * sizeof(float));
    float* bqkv   = (float*)alloc(1536 * sizeof(float));
    bf16* wqkvb = (bf16*)alloc((size_t)3 * C * C * 2);  // [wq; wk; wv]
    bf16* wpb   = (bf16*)alloc((size_t)C * C * 2);
    bf16* xnT   = (bf16*)alloc((size_t)16 * BS * 2);
    bf16* qkT   = (bf16*)alloc((size_t)16 * ES * 2);    // (B,1024,1024): [qT|kT]
    bf16* vv    = (bf16*)alloc((size_t)16 * BS * 2);    // (B,512,1024)
    bf16* O2    = (bf16*)alloc((size_t)16 * BS * 2);

    // Dynamic LDS caps (immediate module state; graph-capture safe).
    hipFuncSetAttribute((const void*)gemm2b<2, 0, 1, bf16>,
                        hipFuncAttributeMaxDynamicSharedMemorySize, 65536);
    hipFuncSetAttribute((const void*)gemm2b<1, 1, 0, float>,
                        hipFuncAttributeMaxDynamicSharedMemorySize, 65536);
    hipFuncSetAttribute((const void*)fattn,
                        hipFuncAttributeMaxDynamicSharedMemorySize, 65536);

    prep<<<1025, 256, 0, stream>>>(wq, wk, wv, wp, wqkvb, wpb, bq, bk, bv, bqkv);

    gn_stats<<<512, 256, 0, stream>>>(x, stats);
    gn_apply_t<<<dim3(32, 16, 16), 256, 0, stream>>>(x, stats, gamma, beta, xnT);

    // QKV proj: M=1024 (i), N=1536 ([q|k|v]), K=512, Z=16. 8x12x16 = 1536 blk.
    gemm2b<2, 0, 1, bf16><<<1536, 256, 65536, stream>>>(
        xnT, BS, 512, wqkvb, 0, 512, qkT, ES, 1024, vv, BS,
        bqkv, nullptr, 0, 0, 512, /*tpb*/96, /*gx*/12);

    const float scale = 0.044194173824159216f; // 512^-0.5
    // Fused attention: 16 batches x 16 i-tiles = 256 blocks, 1/CU.
    fattn<<<256, 256, 65536, stream>>>(qkT, vv, O2, scale);

    // out[o][i] = sum_c wp[o][c] O2[i][c] + bp[o] + x[o][i]. 4x8 tiles x16.
    gemm2b<1, 1, 0, float><<<512, 256, 65536, stream>>>(
        wpb, 0, 512, O2, BS, 512, out, BS, 1024, nullptr, 0,
        bp, x, BS, 1024, 512, /*tpb*/32, /*gx*/8);
}

// Round 8
// 238.531 us; speedup vs baseline: 1.4198x; 1.3982x over previous
//
#include <hip/hip_runtime.h>
#include <hip/hip_bf16.h>

using bf16 = __hip_bfloat16;

typedef __attribute__((ext_vector_type(8))) __bf16 bf16x8;
typedef __attribute__((ext_vector_type(4))) float floatx4;

#define EPS 1e-6f

#define RAW_BARRIER()  asm volatile("s_barrier" ::: "memory")
#define WAIT_VM16()    asm volatile("s_waitcnt vmcnt(16)" ::: "memory")
#define WAIT_VM8()     asm volatile("s_waitcnt vmcnt(8)" ::: "memory")
#define WAIT_VM4()     asm volatile("s_waitcnt vmcnt(4)" ::: "memory")
#define WAIT_VM0()     asm volatile("s_waitcnt vmcnt(0)" ::: "memory")
#define SCHED_FENCE()  __builtin_amdgcn_sched_barrier(0)
#define PRIO1()        __builtin_amdgcn_s_setprio(1)
#define PRIO0()        __builtin_amdgcn_s_setprio(0)

__device__ __forceinline__ void load_lds16(const void* g, void* l) {
    __builtin_amdgcn_global_load_lds(
        (const __attribute__((address_space(1))) void*)g,
        (__attribute__((address_space(3))) void*)l, 16, 0, 0);
}

__device__ __forceinline__ void storeOut(float* p, float v) { *p = v; }
__device__ __forceinline__ void storeOut(bf16* p, float v) { *p = __float2bfloat16(v); }

#define MFMA16(a, b, c) __builtin_amdgcn_mfma_f32_16x16x32_bf16(a, b, c, 0, 0, 0)

// ---------------------------------------------------------------------------
// 2-blocks/CU pipelined NT GEMM: D[m][n] = sum_k A[m][k] * B[n][k]
// BM=BN=128, BK=64 (k-half split), 256 threads = 4 waves (2M x 2N).
// (Unchanged — used for QKV projection and output projection.)
// ---------------------------------------------------------------------------
template <int BIAS_MODE, int RESID_EN, int QKV, typename OutT>
__global__ __launch_bounds__(256, 2) void gemm2b(
    const bf16* __restrict__ A, long long aStride, int lda,
    const bf16* __restrict__ B, long long bStride, int ldb,
    OutT* __restrict__ D, long long dStride, int ldd,
    bf16* __restrict__ vout, long long vStride,
    const float* __restrict__ bias,
    const float* __restrict__ resid, long long rStride, int ldr,
    int K, int tpb, int gx)
{
    constexpr int HB = 8192;   // bytes per (buf, khalf) per operand: 128x32x2B
    extern __shared__ char smem[];

    const unsigned chunk = gridDim.x >> 3;
    const unsigned glob  = (blockIdx.x & 7) * chunk + (blockIdx.x >> 3);
    const unsigned z  = glob / (unsigned)tpb;
    const unsigned t  = glob % (unsigned)tpb;
    const int m0 = (int)(t / (unsigned)gx) << 7;
    const int n0 = (int)(t % (unsigned)gx) << 7;

    const int tid  = threadIdx.x;
    const int lane = tid & 63;
    const int wave = tid >> 6;
    const int wm   = wave >> 1;          // 0..1
    const int wn   = wave & 1;           // 0..1

    const bf16* Ab = A + (size_t)z * aStride + (size_t)m0 * lda;
    const bf16* Bb = B + (size_t)z * bStride + (size_t)n0 * ldb;

    floatx4 acc[4][4];
#pragma unroll
    for (int i = 0; i < 4; ++i)
#pragma unroll
        for (int j = 0; j < 4; ++j) acc[i][j] = (floatx4){0.f, 0.f, 0.f, 0.f};

    const int laneRow = lane & 15;
    const int laneKq  = lane >> 4;
    const int kqs16   = (laneKq ^ ((laneRow >> 1) & 3)) << 4;
    const int arow0   = wm * 64 + laneRow;
    const int brow0   = wn * 64 + laneRow;

    auto stage = [&](int kt, int h) {
        char* Adst = smem + ((kt & 1) * 2 + h) * HB;
        char* Bdst = smem + 4 * HB + ((kt & 1) * 2 + h) * HB;
        const int kb = (kt << 6) + (h << 5);
#pragma unroll
        for (int u = 0; u < 2; ++u) {
            const int idx = tid + u * 256;
            const int r  = idx >> 2;
            const int qs = (idx & 3) ^ ((idx >> 3) & 3);
            load_lds16(Ab + (size_t)r * lda + kb + qs * 8, Adst + idx * 16);
        }
#pragma unroll
        for (int u = 0; u < 2; ++u) {
            const int idx = tid + u * 256;
            const int r  = idx >> 2;
            const int qs = (idx & 3) ^ ((idx >> 3) & 3);
            load_lds16(Bb + (size_t)r * ldb + kb + qs * 8, Bdst + idx * 16);
        }
    };

    const int nt = K >> 6;
    stage(0, 0); stage(0, 1); stage(1, 0);

    for (int kt = 0; kt < nt; ++kt) {
        const char* Ablk = smem + (kt & 1) * 2 * HB;
        const char* Bblk = smem + 4 * HB + (kt & 1) * 2 * HB;
        const bool lastT = (kt == nt - 1);

        // ---- phase 1: k-half 0 ----
        if (lastT) WAIT_VM4(); else WAIT_VM8();
        RAW_BARRIER();
        bf16x8 af[4], bfr[4];
#pragma unroll
        for (int im = 0; im < 4; ++im)
            af[im] = *(const bf16x8*)(Ablk + (arow0 + im * 16) * 64 + kqs16);
#pragma unroll
        for (int in = 0; in < 4; ++in)
            bfr[in] = *(const bf16x8*)(Bblk + (brow0 + in * 16) * 64 + kqs16);
        if (kt + 1 < nt) stage(kt + 1, 1);
        RAW_BARRIER();
        PRIO1();
#pragma unroll
        for (int im = 0; im < 4; ++im)
#pragma unroll
            for (int in = 0; in < 4; ++in)
                acc[im][in] = MFMA16(af[im], bfr[in], acc[im][in]);
        PRIO0();

        // ---- phase 2: k-half 1 ----
        if (lastT) WAIT_VM0(); else WAIT_VM8();
        RAW_BARRIER();
#pragma unroll
        for (int im = 0; im < 4; ++im)
            af[im] = *(const bf16x8*)(Ablk + HB + (arow0 + im * 16) * 64 + kqs16);
#pragma unroll
        for (int in = 0; in < 4; ++in)
            bfr[in] = *(const bf16x8*)(Bblk + HB + (brow0 + in * 16) * 64 + kqs16);
        if (kt + 2 < nt) stage(kt + 2, 0);
        RAW_BARRIER();
        PRIO1();
#pragma unroll
        for (int im = 0; im < 4; ++im)
#pragma unroll
            for (int in = 0; in < 4; ++in)
                acc[im][in] = MFMA16(af[im], bfr[in], acc[im][in]);
        PRIO0();
    }

    // Epilogue. C/D frag layout: col = lane&15, row = (lane>>4)*4 + reg
    const size_t dbase = (size_t)z * dStride;
#pragma unroll
    for (int im = 0; im < 4; ++im) {
        const int gmb = m0 + wm * 64 + im * 16 + (laneKq << 2);
#pragma unroll
        for (int in = 0; in < 4; ++in) {
            const int gn = n0 + wn * 64 + in * 16 + laneRow;
            float bn = 0.f;
            if (BIAS_MODE == 2) bn = bias[gn];
            if (QKV && n0 >= 1024) {
                union { bf16 h[4]; ushort4 u; } pk;
#pragma unroll
                for (int r = 0; r < 4; ++r)
                    pk.h[r] = __float2bfloat16(acc[im][in][r] + bn);
                *(ushort4*)(vout + (size_t)z * vStride +
                            (size_t)(gn - 1024) * 1024 + gmb) = pk.u;
            } else {
#pragma unroll
                for (int r = 0; r < 4; ++r) {
                    const int gm = gmb + r;
                    float v = acc[im][in][r];
                    if (BIAS_MODE == 1) v += bias[gm];
                    if (BIAS_MODE == 2) v += bn;
                    if (RESID_EN)
                        v += resid[(size_t)z * rStride + (size_t)gm * ldr + gn];
                    storeOut(D + dbase + (size_t)gm * ldd + gn, v);
                }
            }
        }
    }
}

// ---------------------------------------------------------------------------
// Fused attention v4 = v1 (R4, 87.8us, proven) + c-split PV.
//   S'[j][i] = K_j . Q_i (swapped), P = exp(scale*S'), rowsum[i] += P,
//   O[c][i] += V[c][j] * P[j][i], O2[i][c] = O / rowsum.
// v1's limiter: LDS pipe (~268 b128-class ops/tile/CU), half of it the
// V-tile read 4x (every wave read all 512 c for its own 16 i).
// v4: PV split by c, not i: wave w computes O[c in 128w..+127][ALL 64 i].
//  - V-reads: wave reads only its 8KB V-slice -> 32 reads/tile/CU (was 128),
//    each vf reused across 4 MFMAs (ni=0..3).
//  - P must be visible to all waves: v1's wave-private P roundtrip becomes
//    block-shared. Write side BYTE-IDENTICAL to v1 (each wave writes its
//    1KB region = P[its 16 i][32 j], row-local granule-XOR). One extra
//    barrier (write->read). Read: pf[ni] = region(ni) at row laneRow,
//    granule laneKq^((laneRow>>1)&3) — v1's exact self-consistent math;
//    row-local XOR means content is reader-independent; 4 waves reading
//    the same addresses broadcast (inter-wave, no conflict).
//  - acc[8][4] floatx4 = 128 regs (same as v1), pf[4] = +16. No R5-style
//    register blowup.
//  - rowsum: wave w's rs covers rows 16w..+15; exchanged via 64-float LDS
//    in the epilogue (each wave needs ri for rows 16*ni+laneRow).
// P-region WAR safety: next tile's P-writes happen after the bottom
// barrier, by which point all waves' P-reads completed. K/V staging,
// vmcnt ledger, XCD swizzle identical to v1.
// LDS ops/tile/CU: ~188 vs 268 -> predict ~650 cy/tile saved.
// ---------------------------------------------------------------------------
__global__ __launch_bounds__(256, 1) void fattn(
    const bf16* __restrict__ qkT,   // (B,1024,1024): row i = [q_i | k_i]
    const bf16* __restrict__ vv,    // (B,512,1024): [c][j]
    bf16* __restrict__ O2,          // (B,1024,512): [i][c]
    float scale)
{
    constexpr int KT = 32768;           // one K- or V-tile: 32KB
    extern __shared__ char smem[];      // [2]K + [2]V = 128KB
    __shared__ __align__(16) char plds[4 * 1024];
    __shared__ float rsLDS[64];

    const int bid  = blockIdx.x;
    const int glob = (bid & 7) * 32 + (bid >> 3);   // XCD-chunked
    const int b    = glob >> 4;
    const int i0   = (glob & 15) << 6;

    const int tid     = threadIdx.x;
    const int lane    = tid & 63;
    const int wave    = tid >> 6;
    const int laneRow = lane & 15;
    const int laneKq  = lane >> 4;
    const int kqs16   = (laneKq ^ ((laneRow >> 1) & 3)) << 4;

    const bf16* Qb = qkT + (size_t)b * 1048576 + (size_t)(i0 + wave * 16) * 1024;
    const bf16* Kb = qkT + (size_t)b * 1048576 + 512;
    const bf16* Vb = vv + (size_t)b * 524288;

    // Q fragments: i = laneRow (+16*wave), k = ks*32 + laneKq*8 .. +8
    bf16x8 qf[16];
#pragma unroll
    for (int ks = 0; ks < 16; ++ks)
        qf[ks] = *(const bf16x8*)(Qb + (size_t)laneRow * 1024 + ks * 32 + laneKq * 8);

    // acc[mf][ni]: c = wave*128 + mf*16 + 4*laneKq + r, i = 16*ni + laneRow
    floatx4 acc[8][4];
#pragma unroll
    for (int mf = 0; mf < 8; ++mf)
#pragma unroll
        for (int ni = 0; ni < 4; ++ni) acc[mf][ni] = (floatx4){0.f, 0.f, 0.f, 0.f};
    float rs = 0.f;

    auto stageK = [&](int jt) {
        char* dst = smem + (jt & 1) * KT;
        const bf16* src = Kb + ((size_t)jt << 5) * 1024;
#pragma unroll
        for (int u = 0; u < 8; ++u) {
            const int idx = tid + u * 256;          // 0..2047
            const int kk = idx >> 7;                // k sub-block 0..15
            const int j  = (idx >> 2) & 31;
            const int p  = idx & 3;
            load_lds16(src + (size_t)j * 1024 + kk * 32 + 8 * (p ^ ((j >> 1) & 3)),
                       dst + idx * 16);
        }
    };
    auto stageV = [&](int jt) {
        char* dst = smem + 2 * KT + (jt & 1) * KT;
        const bf16* src = Vb + (jt << 5);
#pragma unroll
        for (int u = 0; u < 8; ++u) {
            const int idx = tid + u * 256;
            const int c = idx >> 2;                 // 0..511
            const int p = idx & 3;
            load_lds16(src + (size_t)c * 1024 + 8 * (p ^ ((c >> 1) & 3)),
                       dst + idx * 16);
        }
    };

    stageK(0); stageV(0); stageK(1); stageV(1);     // 32 outstanding

    char* plw = plds + wave * 1024 + laneRow * 64;  // own region (write)
    const int sw2 = ((laneRow >> 1) & 3) << 1;      // 8B-granule XOR mask

    for (int jt = 0; jt < 32; ++jt) {
        if (jt == 31) WAIT_VM0(); else WAIT_VM16();
        RAW_BARRIER();
        const char* Kt = smem + (jt & 1) * KT;
        const char* Vt = smem + 2 * KT + (jt & 1) * KT;

        // ---- S' = K_tile . Q : P[j][i (own 16)], j split in 2 m-frags ----
        floatx4 s0 = (floatx4){0.f, 0.f, 0.f, 0.f};
        floatx4 s1 = (floatx4){0.f, 0.f, 0.f, 0.f};
#pragma unroll
        for (int ks = 0; ks < 16; ++ks) {
            bf16x8 kf0 = *(const bf16x8*)(Kt + ks * 2048 + laneRow * 64 + kqs16);
            bf16x8 kf1 = *(const bf16x8*)(Kt + ks * 2048 + (laneRow + 16) * 64 + kqs16);
            s0 = MFMA16(kf0, qf[ks], s0);
            s1 = MFMA16(kf1, qf[ks], s1);
        }

        // ---- exp + rowsum + P -> own LDS region (v1 layout, verbatim) ----
        union { bf16 h[4]; unsigned long long u; } w0, w1;
#pragma unroll
        for (int r = 0; r < 4; ++r) {
            float v0 = __expf(s0[r] * scale);
            float v1 = __expf(s1[r] * scale);
            rs += v0 + v1;
            w0.h[r] = __float2bfloat16(v0);
            w1.h[r] = __float2bfloat16(v1);
        }
        *(unsigned long long*)(plw + ((laneKq)     ^ sw2) * 8) = w0.u;
        *(unsigned long long*)(plw + ((laneKq + 4) ^ sw2) * 8) = w1.u;
        asm volatile("s_waitcnt lgkmcnt(0)" ::: "memory");
        RAW_BARRIER();                   // P visible to all waves
        SCHED_FENCE();
        bf16x8 pf[4];
#pragma unroll
        for (int ni = 0; ni < 4; ++ni)
            pf[ni] = *(const bf16x8*)(plds + ni * 1024 + laneRow * 64 + kqs16);

        // ---- O[c (own 128)][all 64 i] += V . P ----
        PRIO1();
#pragma unroll
        for (int mf = 0; mf < 8; ++mf) {
            bf16x8 vf = *(const bf16x8*)(Vt +
                (wave * 128 + mf * 16 + laneRow) * 64 + kqs16);
#pragma unroll
            for (int ni = 0; ni < 4; ++ni)
                acc[mf][ni] = MFMA16(vf, pf[ni], acc[mf][ni]);
        }
        PRIO0();

        RAW_BARRIER();                   // K/V(jt) reads + P reads done
        if (jt + 2 < 32) { stageK(jt + 2); stageV(jt + 2); }
    }

    // rowsum: wave w holds rs for rows i = 16w + laneRow (after lane-reduce)
    rs += __shfl_xor(rs, 16);
    rs += __shfl_xor(rs, 32);
    if (lane < 16) rsLDS[wave * 16 + lane] = rs;
    __syncthreads();

    // O2[i][c] = acc * ri ; c = wave*128 + mf*16 + 4*laneKq + r, i = 16ni+laneRow
#pragma unroll
    for (int ni = 0; ni < 4; ++ni) {
        const float ri = 1.f / rsLDS[ni * 16 + laneRow];
        bf16* Ob = O2 + (size_t)b * 524288 +
                   (size_t)(i0 + ni * 16 + laneRow) * 512 +
                   wave * 128 + (laneKq << 2);
#pragma unroll
        for (int mf = 0; mf < 8; ++mf) {
            union { bf16 h[4]; ushort4 u; } pk;
#pragma unroll
            for (int r = 0; r < 4; ++r)
                pk.h[r] = __float2bfloat16(acc[mf][ni][r] * ri);
            *(ushort4*)(Ob + mf * 16) = pk.u;
        }
    }
}

// ---------------------------------------------------------------------------
// GroupNorm stats: one block per (b, g); 16 ch x 1024 = 16384 contiguous floats
// ---------------------------------------------------------------------------
__global__ __launch_bounds__(256) void gn_stats(const float* __restrict__ x,
                                                float* __restrict__ stats)
{
    const int bg = blockIdx.x;
    const float4* p = (const float4*)(x + (size_t)bg * 16384);
    float s = 0.f, ss = 0.f;
    for (int i = threadIdx.x; i < 4096; i += 256) {
        float4 v = p[i];
        s  += v.x + v.y + v.z + v.w;
        ss += v.x * v.x + v.y * v.y + v.z * v.z + v.w * v.w;
    }
#pragma unroll
    for (int off = 32; off; off >>= 1) {
        s  += __shfl_down(s, off);
        ss += __shfl_down(ss, off);
    }
    __shared__ float rsm[4], rss[4];
    const int wv = threadIdx.x >> 6;
    if ((threadIdx.x & 63) == 0) { rsm[wv] = s; rss[wv] = ss; }
    __syncthreads();
    if (threadIdx.x == 0) {
        float S  = rsm[0] + rsm[1] + rsm[2] + rsm[3];
        float SS = rss[0] + rss[1] + rss[2] + rss[3];
        float mean = S * (1.f / 16384.f);
        float var  = SS * (1.f / 16384.f) - mean * mean;
        stats[2 * bg]     = mean;
        stats[2 * bg + 1] = rsqrtf(var + EPS);
    }
}

// ---------------------------------------------------------------------------
// GN apply + transpose: x (B,512,1024) fp32 -> xnT (B,1024,512) bf16
// ---------------------------------------------------------------------------
__global__ __launch_bounds__(256) void gn_apply_t(const float* __restrict__ x,
                                                  const float* __restrict__ stats,
                                                  const float* __restrict__ gamma,
                                                  const float* __restrict__ beta,
                                                  bf16* __restrict__ xnT)
{
    __shared__ bf16 tile[32][36];
    const int b = blockIdx.z, c0 = blockIdx.y * 32, i0 = blockIdx.x * 32;
    {
        const int cc = threadIdx.x >> 3;
        const int i4 = (threadIdx.x & 7) << 2;
        const int c  = c0 + cc;
        const float mean = stats[2 * ((b << 5) + (c >> 4))];
        const float rstd = stats[2 * ((b << 5) + (c >> 4)) + 1];
        const float a  = gamma[c] * rstd;
        const float bb = beta[c] - mean * a;
        float4 v = *(const float4*)(x + (((size_t)(b * 512 + c)) << 10) + i0 + i4);
        tile[cc][i4 + 0] = __float2bfloat16(v.x * a + bb);
        tile[cc][i4 + 1] = __float2bfloat16(v.y * a + bb);
        tile[cc][i4 + 2] = __float2bfloat16(v.z * a + bb);
        tile[cc][i4 + 3] = __float2bfloat16(v.w * a + bb);
    }
    __syncthreads();
    {
        const int ii = threadIdx.x >> 3;
        const int c4 = (threadIdx.x & 7) << 2;
        union { bf16 h[4]; uint2 u; } pk;
        pk.h[0] = tile[c4 + 0][ii];
        pk.h[1] = tile[c4 + 1][ii];
        pk.h[2] = tile[c4 + 2][ii];
        pk.h[3] = tile[c4 + 3][ii];
        *((uint2*)(xnT + (((size_t)(b * 1024 + i0 + ii)) << 9) + c0 + c4)) = pk.u;
    }
}

// ---------------------------------------------------------------------------
// prep: weights fp32->bf16 (blocks 0..1023), qkv bias concat (block 1024).
// ---------------------------------------------------------------------------
__global__ __launch_bounds__(256) void prep(
    const float* __restrict__ wq, const float* __restrict__ wk,
    const float* __restrict__ wv, const float* __restrict__ wp,
    bf16* __restrict__ wqkvb, bf16* __restrict__ wpb,
    const float* __restrict__ bq, const float* __restrict__ bk,
    const float* __restrict__ bv, float* __restrict__ bqkv)
{
    const int id = blockIdx.x;
    if (id < 1024) {
        const int w = id >> 8;
        const float* src = (w == 0) ? wq : (w == 1) ? wk : (w == 2) ? wv : wp;
        bf16* dst = (w < 3) ? (wqkvb + (size_t)w * 262144) : wpb;
        const int g = (id & 255) * 256 + threadIdx.x;
        float4 v = ((const float4*)src)[g];
        union { bf16 h[4]; uint2 u; } pk;
        pk.h[0] = __float2bfloat16(v.x);
        pk.h[1] = __float2bfloat16(v.y);
        pk.h[2] = __float2bfloat16(v.z);
        pk.h[3] = __float2bfloat16(v.w);
        ((uint2*)dst)[g] = pk.u;
    } else {
        for (int t = threadIdx.x; t < 1536; t += 256)
            bqkv[t] = (t < 512) ? bq[t] : (t < 1024) ? bk[t - 512] : bv[t - 1024];
    }
}

// ---------------------------------------------------------------------------
extern "C" void kernel_launch(void* const* d_in, const int* in_sizes, int n_in,
                              void* d_out, int out_size, void* d_ws, size_t ws_size,
                              hipStream_t stream)
{
    const float* x     = (const float*)d_in[0];
    const float* gamma = (const float*)d_in[1];
    const float* beta  = (const float*)d_in[2];
    const float* wq    = (const float*)d_in[3];
    const float* bq    = (const float*)d_in[4];
    const float* wk    = (const float*)d_in[5];
    const float* bk    = (const float*)d_in[6];
    const float* wv    = (const float*)d_in[7];
    const float* bv    = (const float*)d_in[8];
    const float* wp    = (const float*)d_in[9];
    const float* bp    = (const float*)d_in[10];
    float* out = (float*)d_out;

    char* ws = (char*)d_ws;
    size_t off = 0;
    auto alloc = [&](size_t bytes) -> char* {
        char* p = ws + off;
        off += (bytes + 255) & ~(size_t)255;
        return p;
    };

    const long long S  = 1024, C = 512;
    const long long BS = S * C;
    const long long ES = S * S;

    float* stats  = (float*)alloc(512 * 2 * sizeof(float));
    float* bqkv   = (float*)alloc(1536 * sizeof(float));
    bf16* wqkvb = (bf16*)alloc((size_t)3 * C * C * 2);  // [wq; wk; wv]
    bf16* wpb   = (bf16*)alloc((size_t)C * C * 2);
    bf16* xnT   = (bf16*)alloc((size_t)16 * BS * 2);
    bf16* qkT   = (bf16*)alloc((size_t)16 * ES * 2);    // (B,1024,1024): [qT|kT]
    bf16* vv    = (bf16*)alloc((size_t)16 * BS * 2);    // (B,512,1024)
    bf16* O2    = (bf16*)alloc((size_t)16 * BS * 2);

    // Dynamic LDS caps (immediate module state; graph-capture safe).
    hipFuncSetAttribute((const void*)gemm2b<2, 0, 1, bf16>,
                        hipFuncAttributeMaxDynamicSharedMemorySize, 65536);
    hipFuncSetAttribute((const void*)gemm2b<1, 1, 0, float>,
                        hipFuncAttributeMaxDynamicSharedMemorySize, 65536);
    hipFuncSetAttribute((const void*)fattn,
                        hipFuncAttributeMaxDynamicSharedMemorySize, 131072);

    prep<<<1025, 256, 0, stream>>>(wq, wk, wv, wp, wqkvb, wpb, bq, bk, bv, bqkv);

    gn_stats<<<512, 256, 0, stream>>>(x, stats);
    gn_apply_t<<<dim3(32, 16, 16), 256, 0, stream>>>(x, stats, gamma, beta, xnT);

    // QKV proj: M=1024 (i), N=1536 ([q|k|v]), K=512, Z=16. 8x12x16 = 1536 blk.
    gemm2b<2, 0, 1, bf16><<<1536, 256, 65536, stream>>>(
        xnT, BS, 512, wqkvb, 0, 512, qkT, ES, 1024, vv, BS,
        bqkv, nullptr, 0, 0, 512, /*tpb*/96, /*gx*/12);

    const float scale = 0.044194173824159216f; // 512^-0.5
    // Fused attention: 16 batches x 16 i-tiles = 256 blocks, 1/CU.
    fattn<<<256, 256, 131072, stream>>>(qkT, vv, O2, scale);

    // out[o][i] = sum_c wp[o][c] O2[i][c] + bp[o] + x[o][i]. 4x8 tiles x16.
    gemm2b<1, 1, 0, float><<<512, 256, 65536, stream>>>(
        wpb, 0, 512, O2, BS, 512, out, BS, 1024, nullptr, 0,
        bp, x, BS, 1024, 512, /*tpb*/32, /*gx*/8);
}